// Round 10
// baseline (239.481 us; speedup 1.0000x reference)
//
#include <hip/hip_runtime.h>
#include <stdint.h>

typedef uint16_t u16;
typedef __attribute__((ext_vector_type(8))) short s8v;      // 8 x bf16 MFMA frag
typedef __attribute__((ext_vector_type(4))) float f32x4;
typedef __attribute__((ext_vector_type(16))) float f32x16;
typedef __attribute__((ext_vector_type(4))) unsigned short us4;
typedef __attribute__((ext_vector_type(4))) unsigned int u32x4;

__device__ __forceinline__ float bf2f(u16 u) {
  union { uint32_t i; float f; } x; x.i = ((uint32_t)u) << 16; return x.f;
}
__device__ __forceinline__ u16 f2bf(float f) {
  union { float f; uint32_t i; } x; x.f = f;
  uint32_t r = (x.i + 0x7FFFu + ((x.i >> 16) & 1u)) >> 16;
  return (u16)r;
}
__device__ __forceinline__ uint32_t cvtpk(float a, float b) {
  uint32_t r;
  asm("v_cvt_pk_bf16_f32 %0, %1, %2" : "=v"(r) : "v"(a), "v"(b));
  return r;
}
__device__ __forceinline__ void gl2lds16(const u16* g, u16* l) {
  __builtin_amdgcn_global_load_lds(
      (const __attribute__((address_space(1))) uint32_t*)g,
      (__attribute__((address_space(3))) uint32_t*)l, 16, 0, 0);
}

// ---------------- GroupNorm stats: one block per (n,g), 8192 contiguous floats ----
__global__ __launch_bounds__(256) void gn_stats_kernel(const float* __restrict__ x,
                                                       float2* __restrict__ stats) {
  const int tid = threadIdx.x;
  const float* p = x + (long)blockIdx.x * 8192;
  float s = 0.f, s2 = 0.f;
#pragma unroll
  for (int it = 0; it < 8; ++it) {
    float4 v = *(const float4*)(p + it * 1024 + tid * 4);
    s  += v.x + v.y + v.z + v.w;
    s2 += v.x * v.x + v.y * v.y + v.z * v.z + v.w * v.w;
  }
#pragma unroll
  for (int off = 32; off >= 1; off >>= 1) {
    s  += __shfl_down(s, off);
    s2 += __shfl_down(s2, off);
  }
  __shared__ float ps[4], ps2[4];
  const int wv = tid >> 6, lane = tid & 63;
  if (lane == 0) { ps[wv] = s; ps2[wv] = s2; }
  __syncthreads();
  if (tid == 0) {
    float S1 = ps[0] + ps[1] + ps[2] + ps[3];
    float S2 = ps2[0] + ps2[1] + ps2[2] + ps2[3];
    float mean = S1 * (1.f / 8192.f);
    float var = S2 * (1.f / 8192.f) - mean * mean;
    stats[blockIdx.x] = make_float2(mean, rsqrtf(var + 1e-6f));
  }
}

// ---------------- weight prep: bf16 copies [o][c]; mats 4..7 transposed -----------
__global__ __launch_bounds__(256) void wprep_kernel(
    const float* __restrict__ s0, const float* __restrict__ s1,
    const float* __restrict__ s2, const float* __restrict__ s3,
    const float* __restrict__ s4, const float* __restrict__ s5,
    const float* __restrict__ s6, const float* __restrict__ s7,
    u16* __restrict__ wbf) {
  const int mat = blockIdx.x, rb = blockIdx.y;
  const float* src = mat==0?s0:mat==1?s1:mat==2?s2:mat==3?s3:mat==4?s4:mat==5?s5:mat==6?s6:s7;
  u16* dst = wbf + mat * 65536 + rb * 16384;
  const int tid = threadIdx.x;
  if (mat < 4) {
    const float* sb = src + rb * 16384;
#pragma unroll
    for (int it = 0; it < 16; ++it) {
      int idx = it * 256 + tid;
      float4 v = *(const float4*)(sb + idx * 4);
      us4 o; o[0]=f2bf(v.x); o[1]=f2bf(v.y); o[2]=f2bf(v.z); o[3]=f2bf(v.w);
      *(us4*)(dst + idx * 4) = o;
    }
  } else {
    __shared__ u16 tl[64][264];
#pragma unroll
    for (int it = 0; it < 16; ++it) {
      int idx = it * 256 + tid;
      int c = idx >> 4, o4 = idx & 15;
      float4 v = *(const float4*)(src + c * 256 + rb * 64 + o4 * 4);
      tl[o4*4+0][c] = f2bf(v.x);
      tl[o4*4+1][c] = f2bf(v.y);
      tl[o4*4+2][c] = f2bf(v.z);
      tl[o4*4+3][c] = f2bf(v.w);
    }
    __syncthreads();
#pragma unroll
    for (int it = 0; it < 16; ++it) {
      int idx = it * 256 + tid;
      int o = idx >> 6, c4 = idx & 63;
      us4 u;
#pragma unroll
      for (int j = 0; j < 4; ++j) u[j] = tl[o][c4*4+j];
      *(us4*)(dst + o * 256 + c4 * 4) = u;
    }
  }
}

// ---------------- fused spatial+temporal q/k/v: one x read, 24 weight tiles -------
__global__ __launch_bounds__(512) void qkvst_kernel(
    const float* __restrict__ x, const float2* __restrict__ stats,
    const float* __restrict__ gamma, const float* __restrict__ beta,
    const u16* __restrict__ wbf,
    const float* __restrict__ bq, const float* __restrict__ bk, const float* __restrict__ bv,
    u16* __restrict__ qb, u16* __restrict__ kb, u16* __restrict__ vb,
    u16* __restrict__ qt, u16* __restrict__ kt, u16* __restrict__ vt) {
  __shared__ float gas[256], bes[256];
  __shared__ u16 ALDS[128 * 256];
  __shared__ u16 WLDS[2][64 * 256];
  const int bid = blockIdx.x;
  const int b = bid >> 7, st = bid & 127;
  const int s0 = st * 128;
  const int tt = s0 >> 10;              // temporal frame
  const int n = b * 16 + tt;            // spatial image
  const int p0 = s0 & 1023;             // hw offset
  const long bbase = (long)b * 4194304;
  const long nbase = (long)n * 262144;
  const int tid = threadIdx.x, w = tid >> 6, lane = tid & 63;
  const int lhi = lane >> 4, llo = lane & 15;

  if (tid < 256) {
    float2 stv = stats[n * 32 + (tid >> 3)];
    float ga = gamma[tid] * stv.y;
    gas[tid] = ga;
    bes[tid] = beta[tid] - stv.x * ga;
  }
  // ---- stage raw A (x^T bf16, swizzled)
  const float* xb = x + bbase + s0;
#pragma unroll
  for (int it = 0; it < 16; ++it) {
    int idx = it * 512 + tid;
    int p = idx & 127, c4 = idx >> 7;
    us4 o;
#pragma unroll
    for (int j = 0; j < 4; ++j)
      o[j] = f2bf(xb[(long)(c4 * 4 + j) * 16384 + p]);
    int ch = c4 >> 1;
    *(us4*)&ALDS[p * 256 + ((ch ^ (p & 7)) << 3) + ((c4 & 1) << 2)] = o;
  }
  __syncthreads();
  // ---- raw frags + in-register GN frags
  const int arow = w * 16 + llo;
  s8v ar[8], ag[8];
#pragma unroll
  for (int kk = 0; kk < 8; ++kk)
    ar[kk] = *(const s8v*)&ALDS[arow * 256 + (((kk * 4 + lhi) ^ (arow & 7)) << 3)];
#pragma unroll
  for (int kk = 0; kk < 8; ++kk) {
    const int cb = kk * 32 + lhi * 8;
    s8v gg;
#pragma unroll
    for (int j = 0; j < 8; ++j)
      gg[j] = (short)f2bf(bf2f((u16)ar[kk][j]) * gas[cb + j] + bes[cb + j]);
    ag[kk] = gg;
  }

  auto stageW4 = [&](int t, int bu) {
    const int mat = (t < 12) ? (t >> 2) : (4 + ((t - 12) >> 2));
    const int sub = (t < 12) ? (t & 3) : ((t - 12) & 3);
    const u16* wsrc = wbf + mat * 65536 + (long)sub * 16384;
#pragma unroll
    for (int ii = 0; ii < 4; ++ii) {
      int s = ii * 512 + tid;           // 0..2047 slots of 16B
      int row = s >> 5, ch = s & 31;
      gl2lds16(wsrc + row * 256 + ((ch ^ (row & 7)) << 3), &WLDS[bu][s * 8]);
    }
  };

  stageW4(0, 0);
  __syncthreads();

  u16* vtl = ALDS;  // reuse for v transpose [64 o][136]
  for (int t = 0; t < 24; ++t) {
    const int cur = t & 1;
    if (t < 23) stageW4(t + 1, cur ^ 1);
    f32x4 acc[4] = {};
    if (t < 12) {
#pragma unroll
      for (int kk = 0; kk < 8; ++kk)
#pragma unroll
        for (int nf = 0; nf < 4; ++nf) {
          int row = nf * 16 + llo;
          s8v bfr = *(const s8v*)&WLDS[cur][row * 256 + (((kk * 4 + lhi) ^ (row & 7)) << 3)];
          acc[nf] = __builtin_amdgcn_mfma_f32_16x16x32_bf16(ag[kk], bfr, acc[nf], 0, 0, 0);
        }
    } else {
#pragma unroll
      for (int kk = 0; kk < 8; ++kk)
#pragma unroll
        for (int nf = 0; nf < 4; ++nf) {
          int row = nf * 16 + llo;
          s8v bfr = *(const s8v*)&WLDS[cur][row * 256 + (((kk * 4 + lhi) ^ (row & 7)) << 3)];
          acc[nf] = __builtin_amdgcn_mfma_f32_16x16x32_bf16(ar[kk], bfr, acc[nf], 0, 0, 0);
        }
    }
    const int o0 = ((t < 12) ? (t & 3) : ((t - 12) & 3)) * 64;
    if (t < 8) {
      u16* dstb = (t < 4) ? qb : kb;
      const float* bias = (t < 4) ? bq : bk;
#pragma unroll
      for (int nf = 0; nf < 4; ++nf) {
        int o = o0 + nf * 16 + llo;
        float b_ = bias[o];
#pragma unroll
        for (int r = 0; r < 4; ++r)
          dstb[nbase + (long)(p0 + w * 16 + lhi * 4 + r) * 256 + o] = f2bf(acc[nf][r] + b_);
      }
    } else if (t < 12) {
#pragma unroll
      for (int nf = 0; nf < 4; ++nf) {
        int o = nf * 16 + llo;
        float b_ = bv[o0 + o];
#pragma unroll
        for (int r = 0; r < 4; ++r)
          vtl[o * 136 + w * 16 + lhi * 4 + r] = f2bf(acc[nf][r] + b_);
      }
      __syncthreads();
#pragma unroll
      for (int ii = 0; ii < 4; ++ii) {
        int i = ii * 512 + tid;
        int o = i >> 5, p4 = (i & 31) * 4;
        us4 u;
#pragma unroll
        for (int j = 0; j < 4; ++j) u[j] = vtl[o * 136 + p4 + j];
        *(us4*)(vb + nbase + (long)(o0 + o) * 1024 + p0 + p4) = u;
      }
    } else {
      u16* dstb = (t < 16) ? qt : (t < 20) ? kt : vt;
#pragma unroll
      for (int nf = 0; nf < 4; ++nf) {
        int o = o0 + nf * 16 + llo;
#pragma unroll
        for (int r = 0; r < 4; ++r)
          dstb[bbase + (long)(s0 + w * 16 + lhi * 4 + r) * 256 + o] = f2bf(acc[nf][r]);
      }
    }
    __syncthreads();
  }
}

// ---------------- flash spatial attention v10 --------------------------------------
// 512 blocks (n x 16 qtiles of 64 rows) x 256 thr, (256,1) so VGPR uncapped (~220).
// 66KB LDS + <=256 VGPR -> HW co-schedules 2 blocks/CU = 2 waves/SIMD naturally;
// cross-block TLP hides single-buffered staging.
__global__ __launch_bounds__(256, 1) void flash_kernel(const u16* __restrict__ qb,
                                                       const u16* __restrict__ kb,
                                                       const u16* __restrict__ vb,
                                                       u16* __restrict__ attb) {
  const int wg = blockIdx.x;
  const int swz = (wg & 7) * 64 + (wg >> 3);  // 4 n per XCD
  const int n = swz >> 4, qt = swz & 15;
  const int tid = threadIdx.x, w = tid >> 6, lane = tid & 63;
  const int q5 = lane & 31, h = lane >> 5;
  const int wq = w & 1;          // q-group (32 rows)
  const int kh = w >> 1;         // k-half (rows kh*32..+32 of each tile)
  const long nbase = (long)n * 262144;

  __shared__ u16 Kb[64 * 256];   // [krow][c] 512B rows, chunk16 ^= (row&7)
  __shared__ u16 Vb[256 * 64];   // [c][j] 128B rows, chunk16 ^= (c&7)
  __shared__ float2 mlbuf[64];

  const int qrow = qt * 64 + wq * 32 + q5;
  const u16* qr = qb + nbase + (long)qrow * 256 + h * 8;
  s8v qa[16];
#pragma unroll
  for (int kk = 0; kk < 16; ++kk) qa[kk] = *(const s8v*)(qr + kk * 16);

  f32x16 oaccT[8] = {};   // O^T: c rows, q col (lane-uniform q)
  float m_ = -3.4e38f, l_ = 0.f;
  constexpr float CEXP = 0.09016844f;  // 0.0625 * log2(e)

  auto stageKV = [&](int jt2) {
    const u16* kbase = kb + nbase + (long)jt2 * 16384;
    const u16* vbase = vb + nbase + (long)jt2 * 64;
#pragma unroll
    for (int ii = 0; ii < 8; ++ii) {
      int s = ii * 256 + tid;           // 0..2047 slots of 16B
      int row = s >> 5, ch = s & 31;
      gl2lds16(kbase + (long)row * 256 + ((ch ^ (row & 7)) << 3), &Kb[s * 8]);
    }
#pragma unroll
    for (int ii = 0; ii < 8; ++ii) {
      int s = ii * 256 + tid;
      int c = s >> 3, ch = s & 7;
      gl2lds16(vbase + (long)c * 1024 + ((ch ^ (c & 7)) << 3), &Vb[s * 8]);
    }
  };

  const int krow = kh * 32 + q5;
  for (int jt = 0; jt < 16; ++jt) {
    stageKV(jt);
    __syncthreads();   // drains gl2lds (vmcnt 0) + orders vs prior compute

    f32x16 sacc = {};
    __builtin_amdgcn_s_setprio(1);
#pragma unroll
    for (int kk = 0; kk < 16; ++kk) {
      s8v kfr = *(const s8v*)&Kb[krow * 256 + (((kk * 2 + h) ^ (krow & 7)) << 3)];
      sacc = __builtin_amdgcn_mfma_f32_32x32x16_bf16(kfr, qa[kk], sacc, 0, 0, 0);
    }
    __builtin_amdgcn_s_setprio(0);
    // ---- tree max (depth 4) instead of 16-deep chain
    float tm[8];
#pragma unroll
    for (int r = 0; r < 8; ++r) tm[r] = fmaxf(sacc[2 * r], sacc[2 * r + 1]);
#pragma unroll
    for (int r = 0; r < 4; ++r) tm[r] = fmaxf(tm[r], tm[r + 4]);
    float pm = fmaxf(fmaxf(tm[0], tm[1]), fmaxf(tm[2], tm[3]));
    pm = fmaxf(pm, __shfl_xor(pm, 32));
    if (!__all(pm <= m_ + 128.f)) {   // defer-max: 128 raw = 8 scaled
      float scf = exp2f((m_ - pm) * CEXP);
      l_ *= scf;
#pragma unroll
      for (int cf = 0; cf < 8; ++cf)
#pragma unroll
        for (int r = 0; r < 16; ++r) oaccT[cf][r] *= scf;
      m_ = pm;
    }
#pragma unroll
    for (int r = 0; r < 16; ++r) sacc[r] = exp2f((sacc[r] - m_) * CEXP);
    // ---- tree sum (depth 4)
    float ts[8];
#pragma unroll
    for (int r = 0; r < 8; ++r) ts[r] = sacc[2 * r] + sacc[2 * r + 1];
#pragma unroll
    for (int r = 0; r < 4; ++r) ts[r] = ts[r] + ts[r + 4];
    float rs = (ts[0] + ts[1]) + (ts[2] + ts[3]);
    rs += __shfl_xor(rs, 32);
    l_ += rs;
    uint32_t pk[4][2];
#pragma unroll
    for (int g = 0; g < 4; ++g) {
      pk[g][0] = cvtpk(sacc[4 * g + 0], sacc[4 * g + 1]);
      pk[g][1] = cvtpk(sacc[4 * g + 2], sacc[4 * g + 3]);
    }
#pragma unroll
    for (int js = 0; js < 2; ++js) {
      uint32_t own0 = pk[2 * js + h][0];
      uint32_t own1 = pk[2 * js + h][1];
      uint32_t snd0 = pk[2 * js + (h ^ 1)][0];
      uint32_t snd1 = pk[2 * js + (h ^ 1)][1];
      uint32_t rcv0 = __shfl_xor(snd0, 32);
      uint32_t rcv1 = __shfl_xor(snd1, 32);
      u32x4 pw;
      pw[0] = h ? rcv0 : own0;
      pw[1] = h ? rcv1 : own1;
      pw[2] = h ? own0 : rcv0;
      pw[3] = h ? own1 : rcv1;
      s8v pa = __builtin_bit_cast(s8v, pw);
      __builtin_amdgcn_s_setprio(1);
#pragma unroll
      for (int cf = 0; cf < 8; ++cf) {
        int c = cf * 32 + q5;
        s8v vfr = *(const s8v*)&Vb[c * 64 + (((kh * 4 + js * 2 + h) ^ (c & 7)) << 3)];
        oaccT[cf] = __builtin_amdgcn_mfma_f32_32x32x16_bf16(vfr, pa, oaccT[cf], 0, 0, 0);
      }
      __builtin_amdgcn_s_setprio(0);
    }
    __syncthreads();   // all waves done reading before next stage overwrites
  }
  // ---- merge epilogue: kh=1 waves dump O^T bf16 + (m,l); kh=0 waves combine ------
  uint32_t* OH = (uint32_t*)&Vb[0];      // [wq][cf][i][h][q5] u32 = 32KB
  u16* tl = &Kb[0];                      // 64 q rows x 256 c bf16, chunk16 ^= (q&7)
  if (kh == 1) {
#pragma unroll
    for (int cf = 0; cf < 8; ++cf)
#pragma unroll
      for (int i = 0; i < 8; ++i)
        OH[(((wq * 8 + cf) * 8 + i) * 2 + h) * 32 + q5] =
            cvtpk(oaccT[cf][2 * i], oaccT[cf][2 * i + 1]);
    if (h == 0) mlbuf[wq * 32 + q5] = make_float2(m_, l_);
  }
  __syncthreads();
  if (kh == 0) {
    float2 pml = mlbuf[wq * 32 + q5];
    float M = fmaxf(m_, pml.x);
    float alo = exp2f((m_ - M) * CEXP);
    float ahi = exp2f((pml.x - M) * CEXP);
    float linv = 1.f / (l_ * alo + pml.y * ahi);
    float slo = alo * linv, shi = ahi * linv;
    const int myq = wq * 32 + q5;
#pragma unroll
    for (int cf = 0; cf < 8; ++cf) {
      float v[16];
#pragma unroll
      for (int i = 0; i < 8; ++i) {
        uint32_t pv = OH[(((wq * 8 + cf) * 8 + i) * 2 + h) * 32 + q5];
        v[2 * i]     = oaccT[cf][2 * i] * slo + bf2f((u16)(pv & 0xffff)) * shi;
        v[2 * i + 1] = oaccT[cf][2 * i + 1] * slo + bf2f((u16)(pv >> 16)) * shi;
      }
#pragma unroll
      for (int g = 0; g < 4; ++g) {
        uint2 val;
        val.x = cvtpk(v[4 * g + 0], v[4 * g + 1]);
        val.y = cvtpk(v[4 * g + 2], v[4 * g + 3]);
        int ch = (cf * 4 + g) ^ (myq & 7);
        *(uint2*)&tl[myq * 256 + ch * 8 + h * 4] = val;
      }
    }
  }
  __syncthreads();
  // ---- coalesced global write from tl (64 rows x 256 c)
  const int qo = tid >> 2, qu = tid & 3;
  u16* obase = attb + nbase + (long)(qt * 64 + qo) * 256;
#pragma unroll
  for (int u = 0; u < 8; ++u) {
    int c16 = qu * 8 + u;
    u32x4 vv = *(const u32x4*)&tl[qo * 256 + ((c16 ^ (qo & 7)) << 3)];
    *(u32x4*)(obase + c16 * 8) = vv;
  }
}

// ---------------- temporal axial attention (unchanged) -----------------------------
__global__ __launch_bounds__(256) void tattn_kernel(const u16* __restrict__ qt,
                                                    const u16* __restrict__ kt,
                                                    const u16* __restrict__ vt,
                                                    u16* __restrict__ ot) {
  const int bi = blockIdx.x >> 10, hw = blockIdx.x & 1023;
  const long base = (long)bi * 4194304 + (long)hw * 256;
  __shared__ float qs[16][260], ks[16][260], vs[16][260];
  __shared__ u16 os[16][256];
  const int tid = threadIdx.x;
#pragma unroll
  for (int it = 0; it < 4; ++it) {
    int idx = it * 256 + tid;
    int t = idx >> 6, cv = idx & 63;
    long g = base + (long)t * 262144 + cv * 4;
    us4 a = *(const us4*)(qt + g);
    us4 b = *(const us4*)(kt + g);
    us4 c = *(const us4*)(vt + g);
#pragma unroll
    for (int j = 0; j < 4; ++j) {
      qs[t][cv * 4 + j] = bf2f(a[j]);
      ks[t][cv * 4 + j] = bf2f(b[j]);
      vs[t][cv * 4 + j] = bf2f(c[j]);
    }
  }
  __syncthreads();
  if (tid < 128) {
    const int h = tid >> 4, t = tid & 15;
    const int c0 = h * 32;
    float sc[16];
    float mx = -3.4e38f;
#pragma unroll
    for (int t2 = 0; t2 < 16; ++t2) {
      float d = 0.f;
#pragma unroll
      for (int dd = 0; dd < 32; ++dd) d += qs[t][c0 + dd] * ks[t2][c0 + dd];
      sc[t2] = d * 0.17677669529663687f;
      mx = fmaxf(mx, sc[t2]);
    }
    float sum = 0.f;
#pragma unroll
    for (int t2 = 0; t2 < 16; ++t2) { sc[t2] = __expf(sc[t2] - mx); sum += sc[t2]; }
    float inv = 1.f / sum;
#pragma unroll
    for (int dd = 0; dd < 32; ++dd) {
      float o = 0.f;
#pragma unroll
      for (int t2 = 0; t2 < 16; ++t2) o += sc[t2] * vs[t2][c0 + dd];
      os[t][c0 + dd] = f2bf(o * inv);
    }
  }
  __syncthreads();
#pragma unroll
  for (int it = 0; it < 4; ++it) {
    int idx = it * 256 + tid;
    int t = idx >> 6, cv = idx & 63;
    us4 o4;
#pragma unroll
    for (int j = 0; j < 4; ++j) o4[j] = os[t][cv * 4 + j];
    *(us4*)(ot + base + (long)t * 262144 + cv * 4) = o4;
  }
}

// ---------------- temporal final projection -> tmpT[b][co][s] bf16 -----------------
__global__ __launch_bounds__(512) void tfinal_kernel(
    const u16* __restrict__ ott, const u16* __restrict__ wbf,
    u16* __restrict__ tmpT) {
  __shared__ u16 ALDS[128 * 256];
  __shared__ u16 WLDS[2][64 * 256];
  const int bid = blockIdx.x;
  const int b = bid >> 7, st = bid & 127;
  const int s0 = st * 128;
  const int tid = threadIdx.x, w = tid >> 6, lane = tid & 63;
  const int lhi = lane >> 4, llo = lane & 15;
  const long bbase = (long)b * 4194304;

  const u16* otS = ott + bbase + (long)s0 * 256;
#pragma unroll
  for (int ii = 0; ii < 8; ++ii) {
    int i0 = (w * 8 + ii) * 64;
    int g = i0 + lane;
    int row = g >> 5, ch = g & 31;
    gl2lds16(otS + row * 256 + ((ch ^ (row & 7)) << 3), &ALDS[i0 * 8]);
  }
  __syncthreads();
  const int arow = w * 16 + llo;
  s8v qa[8];
#pragma unroll
  for (int kk = 0; kk < 8; ++kk)
    qa[kk] = *(const s8v*)&ALDS[arow * 256 + (((kk * 4 + lhi) ^ (arow & 7)) << 3)];

  auto stageW = [&](int t, int bu) {
    const u16* wsrc = wbf + 7 * 65536 + (long)t * 16384;
#pragma unroll
    for (int ii = 0; ii < 4; ++ii) {
      int i0 = (w * 4 + ii) * 64;
      int g = i0 + lane;
      int row = g >> 5, ch = g & 31;
      gl2lds16(wsrc + row * 256 + ((ch ^ (row & 7)) << 3), &WLDS[bu][i0 * 8]);
    }
  };
  stageW(0, 0);
  __syncthreads();
  u16* vtl = ALDS;  // safe: frags already in regs
  for (int t = 0; t < 4; ++t) {
    const int cur = t & 1;
    if (t < 3) stageW(t + 1, cur ^ 1);
    f32x4 acc[4] = {};
#pragma unroll
    for (int kk = 0; kk < 8; ++kk)
#pragma unroll
      for (int nf = 0; nf < 4; ++nf) {
        int row = nf * 16 + llo;
        s8v bb = *(const s8v*)&WLDS[cur][row * 256 + (((kk * 4 + lhi) ^ (row & 7)) << 3)];
        acc[nf] = __builtin_amdgcn_mfma_f32_16x16x32_bf16(qa[kk], bb, acc[nf], 0, 0, 0);
      }
#pragma unroll
    for (int nf = 0; nf < 4; ++nf) {
      int o = nf * 16 + llo;
#pragma unroll
      for (int r = 0; r < 4; ++r)
        vtl[o * 136 + w * 16 + lhi * 4 + r] = f2bf(acc[nf][r]);
    }
    __syncthreads();
    const int o0 = t * 64;
#pragma unroll
    for (int ii = 0; ii < 4; ++ii) {
      int i = ii * 512 + tid;
      int o = i >> 5, p4 = (i & 31) * 4;
      us4 uu;
#pragma unroll
      for (int j = 0; j < 4; ++j) uu[j] = vtl[o * 136 + p4 + j];
      *(us4*)(tmpT + bbase + (long)(o0 + o) * 16384 + s0 + p4) = uu;
    }
    __syncthreads();
  }
}

// ---------------- fused output: out = x + bo + bf + wo.att + tmpT ------------------
__global__ __launch_bounds__(256) void outproj_kernel(
    const float* __restrict__ x, const u16* __restrict__ attb,
    const u16* __restrict__ tmpT, const u16* __restrict__ wbf,
    const float* __restrict__ bo, const float* __restrict__ bf,
    float* __restrict__ out) {
  __shared__ u16 attL[64 * 256];
  const int u = blockIdx.x;
  const int wkx = (u & 7) * 256 + (u >> 3);  // XCD-chunk swizzle (2048 % 8 == 0)
  const int otile = wkx & 3, pt = (wkx >> 2) & 15, n = wkx >> 6;
  const int b = n >> 4;
  const int o0 = otile * 64, p0 = pt * 64;
  const int tid = threadIdx.x, w = tid >> 6, lane = tid & 63;
  const int lhi = lane >> 4, llo = lane & 15;
  const long nbase = (long)n * 262144;

  const u16* attS = attb + nbase + (long)p0 * 256;
#pragma unroll
  for (int ii = 0; ii < 8; ++ii) {
    int i0 = (w * 8 + ii) * 64;
    int g = i0 + lane;
    int row = g >> 5, ch = g & 31;
    gl2lds16(attS + row * 256 + ((ch ^ (row & 7)) << 3), &attL[i0 * 8]);
  }
  const u16* woR = wbf + 3 * 65536 + (long)(o0 + w * 16 + llo) * 256;
  s8v woa[8];
#pragma unroll
  for (int kk = 0; kk < 8; ++kk)
    woa[kk] = *(const s8v*)(woR + kk * 32 + lhi * 8);
  __syncthreads();
  f32x4 acc[4] = {};
#pragma unroll
  for (int kk = 0; kk < 8; ++kk)
#pragma unroll
    for (int nf = 0; nf < 4; ++nf) {
      int row = nf * 16 + llo;
      s8v b1 = *(const s8v*)&attL[row * 256 + (((kk * 4 + lhi) ^ (row & 7)) << 3)];
      acc[nf] = __builtin_amdgcn_mfma_f32_16x16x32_bf16(woa[kk], b1, acc[nf], 0, 0, 0);
    }
#pragma unroll
  for (int r = 0; r < 4; ++r) {
    int cp = o0 + w * 16 + lhi * 4 + r;          // output channel c'
    int co = ((n & 15) << 4) + (cp >> 4);        // temporal channel
    int tt = cp & 15;                            // temporal t
    float bias = bo[cp] + bf[co];
    const u16* tr = tmpT + (long)b * 4194304 + (long)co * 16384 + tt * 1024 + p0;
    const float* xr = x + nbase + (long)cp * 1024 + p0;
    float* orow = out + nbase + (long)cp * 1024 + p0;
#pragma unroll
    for (int nf = 0; nf < 4; ++nf) {
      int p = nf * 16 + llo;
      orow[p] = acc[nf][r] + bias + xr[p] + bf2f(tr[p]);
    }
  }
}

// =================================================================================
extern "C" void kernel_launch(void* const* d_in, const int* in_sizes, int n_in,
                              void* d_out, int out_size, void* d_ws, size_t ws_size,
                              hipStream_t stream) {
  const float* x     = (const float*)d_in[0];
  const float* gam   = (const float*)d_in[1];
  const float* bet   = (const float*)d_in[2];
  const float* wq_s  = (const float*)d_in[3];
  const float* bq_s  = (const float*)d_in[4];
  const float* wk_s  = (const float*)d_in[5];
  const float* bk_s  = (const float*)d_in[6];
  const float* wv_s  = (const float*)d_in[7];
  const float* bv_s  = (const float*)d_in[8];
  const float* wo_s  = (const float*)d_in[9];
  const float* bo_s  = (const float*)d_in[10];
  const float* wq_t  = (const float*)d_in[11];
  const float* wk_t  = (const float*)d_in[12];
  const float* wv_t  = (const float*)d_in[13];
  const float* wf_t  = (const float*)d_in[14];
  const float* bf_t  = (const float*)d_in[15];
  float* out = (float*)d_out;

  u16* qb   = (u16*)d_ws;           // [32][1024][256]
  u16* kb   = qb + 8388608;         // [32][1024][256]
  u16* vb   = kb + 8388608;         // [32][256][1024]
  u16* attb = vb + 8388608;         // [32][1024][256]
  u16* ottb = attb + 8388608;       // [2][16384][256]
  u16* wbf  = ottb + 8388608;       // 8 x [256][256] bf16
  u16* qtb  = wbf + 524288;         // [2][16384][256]
  u16* ktb  = qtb + 8388608;
  u16* vtb  = ktb + 8388608;
  float2* stats = (float2*)(vtb + 8388608);
  u16* tmpT = qtb;                  // dead post-tattn

  gn_stats_kernel<<<1024, 256, 0, stream>>>(x, stats);
  wprep_kernel<<<dim3(8, 4), 256, 0, stream>>>(wq_s, wk_s, wv_s, wo_s,
                                               wq_t, wk_t, wv_t, wf_t, wbf);
  qkvst_kernel<<<256, 512, 0, stream>>>(x, stats, gam, bet, wbf,
                                        bq_s, bk_s, bv_s, qb, kb, vb, qtb, ktb, vtb);
  flash_kernel<<<512, 256, 0, stream>>>(qb, kb, vb, attb);
  tattn_kernel<<<2048, 256, 0, stream>>>(qtb, ktb, vtb, ottb);
  tfinal_kernel<<<256, 512, 0, stream>>>(ottb, wbf, tmpT);
  outproj_kernel<<<2048, 256, 0, stream>>>(x, attb, tmpT, wbf, bo_s, bf_t, out);
}

// Round 11
// 206.229 us; speedup vs baseline: 1.1612x; 1.1612x over previous
//
#include <hip/hip_runtime.h>
#include <stdint.h>

typedef uint16_t u16;
typedef __attribute__((ext_vector_type(8))) short s8v;      // 8 x bf16 MFMA frag
typedef __attribute__((ext_vector_type(4))) float f32x4;
typedef __attribute__((ext_vector_type(16))) float f32x16;
typedef __attribute__((ext_vector_type(4))) unsigned short us4;
typedef __attribute__((ext_vector_type(4))) unsigned int u32x4;

__device__ __forceinline__ float bf2f(u16 u) {
  union { uint32_t i; float f; } x; x.i = ((uint32_t)u) << 16; return x.f;
}
__device__ __forceinline__ u16 f2bf(float f) {
  union { float f; uint32_t i; } x; x.f = f;
  uint32_t r = (x.i + 0x7FFFu + ((x.i >> 16) & 1u)) >> 16;
  return (u16)r;
}
__device__ __forceinline__ uint32_t cvtpk(float a, float b) {
  uint32_t r;
  asm("v_cvt_pk_bf16_f32 %0, %1, %2" : "=v"(r) : "v"(a), "v"(b));
  return r;
}
__device__ __forceinline__ void gl2lds16(const u16* g, u16* l) {
  __builtin_amdgcn_global_load_lds(
      (const __attribute__((address_space(1))) uint32_t*)g,
      (__attribute__((address_space(3))) uint32_t*)l, 16, 0, 0);
}

// ---------------- GroupNorm stats: one block per (n,g), 8192 contiguous floats ----
__global__ __launch_bounds__(256) void gn_stats_kernel(const float* __restrict__ x,
                                                       float2* __restrict__ stats) {
  const int tid = threadIdx.x;
  const float* p = x + (long)blockIdx.x * 8192;
  float s = 0.f, s2 = 0.f;
#pragma unroll
  for (int it = 0; it < 8; ++it) {
    float4 v = *(const float4*)(p + it * 1024 + tid * 4);
    s  += v.x + v.y + v.z + v.w;
    s2 += v.x * v.x + v.y * v.y + v.z * v.z + v.w * v.w;
  }
#pragma unroll
  for (int off = 32; off >= 1; off >>= 1) {
    s  += __shfl_down(s, off);
    s2 += __shfl_down(s2, off);
  }
  __shared__ float ps[4], ps2[4];
  const int wv = tid >> 6, lane = tid & 63;
  if (lane == 0) { ps[wv] = s; ps2[wv] = s2; }
  __syncthreads();
  if (tid == 0) {
    float S1 = ps[0] + ps[1] + ps[2] + ps[3];
    float S2 = ps2[0] + ps2[1] + ps2[2] + ps2[3];
    float mean = S1 * (1.f / 8192.f);
    float var = S2 * (1.f / 8192.f) - mean * mean;
    stats[blockIdx.x] = make_float2(mean, rsqrtf(var + 1e-6f));
  }
}

// ---------------- weight prep: bf16 copies [o][c]; mats 4..7 transposed -----------
__global__ __launch_bounds__(256) void wprep_kernel(
    const float* __restrict__ s0, const float* __restrict__ s1,
    const float* __restrict__ s2, const float* __restrict__ s3,
    const float* __restrict__ s4, const float* __restrict__ s5,
    const float* __restrict__ s6, const float* __restrict__ s7,
    u16* __restrict__ wbf) {
  const int mat = blockIdx.x, rb = blockIdx.y;
  const float* src = mat==0?s0:mat==1?s1:mat==2?s2:mat==3?s3:mat==4?s4:mat==5?s5:mat==6?s6:s7;
  u16* dst = wbf + mat * 65536 + rb * 16384;
  const int tid = threadIdx.x;
  if (mat < 4) {
    const float* sb = src + rb * 16384;
#pragma unroll
    for (int it = 0; it < 16; ++it) {
      int idx = it * 256 + tid;
      float4 v = *(const float4*)(sb + idx * 4);
      us4 o; o[0]=f2bf(v.x); o[1]=f2bf(v.y); o[2]=f2bf(v.z); o[3]=f2bf(v.w);
      *(us4*)(dst + idx * 4) = o;
    }
  } else {
    __shared__ u16 tl[64][264];
#pragma unroll
    for (int it = 0; it < 16; ++it) {
      int idx = it * 256 + tid;
      int c = idx >> 4, o4 = idx & 15;
      float4 v = *(const float4*)(src + c * 256 + rb * 64 + o4 * 4);
      tl[o4*4+0][c] = f2bf(v.x);
      tl[o4*4+1][c] = f2bf(v.y);
      tl[o4*4+2][c] = f2bf(v.z);
      tl[o4*4+3][c] = f2bf(v.w);
    }
    __syncthreads();
#pragma unroll
    for (int it = 0; it < 16; ++it) {
      int idx = it * 256 + tid;
      int o = idx >> 6, c4 = idx & 63;
      us4 u;
#pragma unroll
      for (int j = 0; j < 4; ++j) u[j] = tl[o][c4*4+j];
      *(us4*)(dst + o * 256 + c4 * 4) = u;
    }
  }
}

// ---------------- fused spatial+temporal q/k/v: one x read, 24 weight tiles -------
__global__ __launch_bounds__(512) void qkvst_kernel(
    const float* __restrict__ x, const float2* __restrict__ stats,
    const float* __restrict__ gamma, const float* __restrict__ beta,
    const u16* __restrict__ wbf,
    const float* __restrict__ bq, const float* __restrict__ bk, const float* __restrict__ bv,
    u16* __restrict__ qb, u16* __restrict__ kb, u16* __restrict__ vb,
    u16* __restrict__ qt, u16* __restrict__ kt, u16* __restrict__ vt) {
  __shared__ float gas[256], bes[256];
  __shared__ u16 ALDS[128 * 256];
  __shared__ u16 WLDS[2][64 * 256];
  const int bid = blockIdx.x;
  const int b = bid >> 7, st = bid & 127;
  const int s0 = st * 128;
  const int tt = s0 >> 10;              // temporal frame
  const int n = b * 16 + tt;            // spatial image
  const int p0 = s0 & 1023;             // hw offset
  const long bbase = (long)b * 4194304;
  const long nbase = (long)n * 262144;
  const int tid = threadIdx.x, w = tid >> 6, lane = tid & 63;
  const int lhi = lane >> 4, llo = lane & 15;

  if (tid < 256) {
    float2 stv = stats[n * 32 + (tid >> 3)];
    float ga = gamma[tid] * stv.y;
    gas[tid] = ga;
    bes[tid] = beta[tid] - stv.x * ga;
  }
  // ---- stage raw A (x^T bf16, swizzled)
  const float* xb = x + bbase + s0;
#pragma unroll
  for (int it = 0; it < 16; ++it) {
    int idx = it * 512 + tid;
    int p = idx & 127, c4 = idx >> 7;
    us4 o;
#pragma unroll
    for (int j = 0; j < 4; ++j)
      o[j] = f2bf(xb[(long)(c4 * 4 + j) * 16384 + p]);
    int ch = c4 >> 1;
    *(us4*)&ALDS[p * 256 + ((ch ^ (p & 7)) << 3) + ((c4 & 1) << 2)] = o;
  }
  __syncthreads();
  // ---- raw frags + in-register GN frags
  const int arow = w * 16 + llo;
  s8v ar[8], ag[8];
#pragma unroll
  for (int kk = 0; kk < 8; ++kk)
    ar[kk] = *(const s8v*)&ALDS[arow * 256 + (((kk * 4 + lhi) ^ (arow & 7)) << 3)];
#pragma unroll
  for (int kk = 0; kk < 8; ++kk) {
    const int cb = kk * 32 + lhi * 8;
    s8v gg;
#pragma unroll
    for (int j = 0; j < 8; ++j)
      gg[j] = (short)f2bf(bf2f((u16)ar[kk][j]) * gas[cb + j] + bes[cb + j]);
    ag[kk] = gg;
  }

  auto stageW4 = [&](int t, int bu) {
    const int mat = (t < 12) ? (t >> 2) : (4 + ((t - 12) >> 2));
    const int sub = (t < 12) ? (t & 3) : ((t - 12) & 3);
    const u16* wsrc = wbf + mat * 65536 + (long)sub * 16384;
#pragma unroll
    for (int ii = 0; ii < 4; ++ii) {
      int s = ii * 512 + tid;           // 0..2047 slots of 16B
      int row = s >> 5, ch = s & 31;
      gl2lds16(wsrc + row * 256 + ((ch ^ (row & 7)) << 3), &WLDS[bu][s * 8]);
    }
  };

  stageW4(0, 0);
  __syncthreads();

  u16* vtl = ALDS;  // reuse for v transpose [64 o][136]
  for (int t = 0; t < 24; ++t) {
    const int cur = t & 1;
    if (t < 23) stageW4(t + 1, cur ^ 1);
    f32x4 acc[4] = {};
    if (t < 12) {
#pragma unroll
      for (int kk = 0; kk < 8; ++kk)
#pragma unroll
        for (int nf = 0; nf < 4; ++nf) {
          int row = nf * 16 + llo;
          s8v bfr = *(const s8v*)&WLDS[cur][row * 256 + (((kk * 4 + lhi) ^ (row & 7)) << 3)];
          acc[nf] = __builtin_amdgcn_mfma_f32_16x16x32_bf16(ag[kk], bfr, acc[nf], 0, 0, 0);
        }
    } else {
#pragma unroll
      for (int kk = 0; kk < 8; ++kk)
#pragma unroll
        for (int nf = 0; nf < 4; ++nf) {
          int row = nf * 16 + llo;
          s8v bfr = *(const s8v*)&WLDS[cur][row * 256 + (((kk * 4 + lhi) ^ (row & 7)) << 3)];
          acc[nf] = __builtin_amdgcn_mfma_f32_16x16x32_bf16(ar[kk], bfr, acc[nf], 0, 0, 0);
        }
    }
    const int o0 = ((t < 12) ? (t & 3) : ((t - 12) & 3)) * 64;
    if (t < 8) {
      u16* dstb = (t < 4) ? qb : kb;
      const float* bias = (t < 4) ? bq : bk;
#pragma unroll
      for (int nf = 0; nf < 4; ++nf) {
        int o = o0 + nf * 16 + llo;
        float b_ = bias[o];
#pragma unroll
        for (int r = 0; r < 4; ++r)
          dstb[nbase + (long)(p0 + w * 16 + lhi * 4 + r) * 256 + o] = f2bf(acc[nf][r] + b_);
      }
    } else if (t < 12) {
#pragma unroll
      for (int nf = 0; nf < 4; ++nf) {
        int o = nf * 16 + llo;
        float b_ = bv[o0 + o];
#pragma unroll
        for (int r = 0; r < 4; ++r)
          vtl[o * 136 + w * 16 + lhi * 4 + r] = f2bf(acc[nf][r] + b_);
      }
      __syncthreads();
#pragma unroll
      for (int ii = 0; ii < 4; ++ii) {
        int i = ii * 512 + tid;
        int o = i >> 5, p4 = (i & 31) * 4;
        us4 u;
#pragma unroll
        for (int j = 0; j < 4; ++j) u[j] = vtl[o * 136 + p4 + j];
        *(us4*)(vb + nbase + (long)(o0 + o) * 1024 + p0 + p4) = u;
      }
    } else {
      u16* dstb = (t < 16) ? qt : (t < 20) ? kt : vt;
#pragma unroll
      for (int nf = 0; nf < 4; ++nf) {
        int o = o0 + nf * 16 + llo;
#pragma unroll
        for (int r = 0; r < 4; ++r)
          dstb[bbase + (long)(s0 + w * 16 + lhi * 4 + r) * 256 + o] = f2bf(acc[nf][r]);
      }
    }
    __syncthreads();
  }
}

// ---------------- flash spatial attention v11 = v4 (best measured) + tree reductions
// 256 blocks (32 n x 8 qtiles of 128 rows), 4 waves x 32 q-rows, 32x32x16 MFMA,
// double-buffered K/V via gl2lds, (256,1) -> VGPR ~228 no spill, 1 wave/SIMD.
__global__ __launch_bounds__(256, 1) void flash_kernel(const u16* __restrict__ qb,
                                                       const u16* __restrict__ kb,
                                                       const u16* __restrict__ vb,
                                                       u16* __restrict__ attb) {
  const int wg = blockIdx.x;
  const int swz = (wg & 7) * 32 + (wg >> 3);  // 4 n per XCD
  const int n = swz >> 3, qt = swz & 7;
  const int tid = threadIdx.x, w = tid >> 6, lane = tid & 63;
  const int q5 = lane & 31, h = lane >> 5;
  const long nbase = (long)n * 262144;

  __shared__ u16 Kb[2][64 * 256];  // [krow][c] 512B rows, chunk16 ^= (row&7)
  __shared__ u16 Vb[2][256 * 64];  // [c][j] 128B rows, chunk16 ^= (c&7)

  // Q fragments: B-operand, 32 q-rows per wave, k = kk*16 + h*8 + j
  const int qrow = qt * 128 + w * 32 + q5;
  const u16* qr = qb + nbase + (long)qrow * 256 + h * 8;
  s8v qa[16];
#pragma unroll
  for (int kk = 0; kk < 16; ++kk) qa[kk] = *(const s8v*)(qr + kk * 16);

  f32x16 oaccT[8] = {};   // O^T: c rows, q col (lane-uniform q)
  float m_ = -3.4e38f, l_ = 0.f;
  constexpr float CEXP = 0.09016844f;  // 0.0625 * log2(e)

  auto stageKV = [&](int jt2, int b) {
    const u16* kbase = kb + nbase + (long)jt2 * 16384;
    const u16* vbase = vb + nbase + (long)jt2 * 64;
#pragma unroll
    for (int ii = 0; ii < 8; ++ii) {
      int slot = ii * 256 + tid;
      int row = slot >> 5, ch = slot & 31;
      gl2lds16(kbase + (long)row * 256 + ((ch ^ (row & 7)) << 3), &Kb[b][slot * 8]);
    }
#pragma unroll
    for (int ii = 0; ii < 8; ++ii) {
      int slot = ii * 256 + tid;
      int c = slot >> 3, ch = slot & 7;
      gl2lds16(vbase + (long)c * 1024 + ((ch ^ (c & 7)) << 3), &Vb[b][slot * 8]);
    }
  };

  stageKV(0, 0);
  __syncthreads();

  for (int jt = 0; jt < 16; ++jt) {
    const int cur = jt & 1;
    if (jt < 15) stageKV(jt + 1, cur ^ 1);

    // ---- QK^T swapped: sacc[f] = S^T[k=f*32+...][q]
    f32x16 sacc[2] = {};
    __builtin_amdgcn_s_setprio(1);
#pragma unroll
    for (int kk = 0; kk < 16; ++kk) {
#pragma unroll
      for (int f = 0; f < 2; ++f) {
        int krow = f * 32 + q5;
        s8v kfr = *(const s8v*)&Kb[cur][krow * 256 + (((kk * 2 + h) ^ (q5 & 7)) << 3)];
        sacc[f] = __builtin_amdgcn_mfma_f32_32x32x16_bf16(kfr, qa[kk], sacc[f], 0, 0, 0);
      }
    }
    __builtin_amdgcn_s_setprio(0);
    // ---- softmax (raw-domain max, scale folded into exp2), tree reductions
    float tm[16];
#pragma unroll
    for (int r = 0; r < 16; ++r) tm[r] = fmaxf(sacc[0][r], sacc[1][r]);
#pragma unroll
    for (int r = 0; r < 8; ++r) tm[r] = fmaxf(tm[r], tm[r + 8]);
#pragma unroll
    for (int r = 0; r < 4; ++r) tm[r] = fmaxf(tm[r], tm[r + 4]);
    float pm = fmaxf(fmaxf(tm[0], tm[1]), fmaxf(tm[2], tm[3]));
    pm = fmaxf(pm, __shfl_xor(pm, 32));
    if (!__all(pm <= m_ + 128.f)) {   // defer-max: 128 raw = 8 scaled
      float scf = exp2f((m_ - pm) * CEXP);
      l_ *= scf;
#pragma unroll
      for (int cf = 0; cf < 8; ++cf)
#pragma unroll
        for (int r = 0; r < 16; ++r) oaccT[cf][r] *= scf;
      m_ = pm;
    }
#pragma unroll
    for (int f = 0; f < 2; ++f)
#pragma unroll
      for (int r = 0; r < 16; ++r) sacc[f][r] = exp2f((sacc[f][r] - m_) * CEXP);
    float ts[16];
#pragma unroll
    for (int r = 0; r < 16; ++r) ts[r] = sacc[0][r] + sacc[1][r];
#pragma unroll
    for (int r = 0; r < 8; ++r) ts[r] = ts[r] + ts[r + 8];
#pragma unroll
    for (int r = 0; r < 4; ++r) ts[r] = ts[r] + ts[r + 4];
    float rs = (ts[0] + ts[1]) + (ts[2] + ts[3]);
    rs += __shfl_xor(rs, 32);
    l_ += rs;
    // ---- pack P to bf16 pairs
    uint32_t pk[2][4][2];
#pragma unroll
    for (int f = 0; f < 2; ++f)
#pragma unroll
      for (int g = 0; g < 4; ++g) {
        pk[f][g][0] = cvtpk(sacc[f][4 * g + 0], sacc[f][4 * g + 1]);
        pk[f][g][1] = cvtpk(sacc[f][4 * g + 2], sacc[f][4 * g + 3]);
      }
    // ---- PV: O^T += mfma(V^T, P) over 4 j-slices
#pragma unroll
    for (int js = 0; js < 4; ++js) {
      const int f = js >> 1, g0 = 2 * (js & 1);
      uint32_t own0 = h ? pk[f][g0 + 1][0] : pk[f][g0][0];
      uint32_t own1 = h ? pk[f][g0 + 1][1] : pk[f][g0][1];
      uint32_t snd0 = h ? pk[f][g0][0] : pk[f][g0 + 1][0];
      uint32_t snd1 = h ? pk[f][g0][1] : pk[f][g0 + 1][1];
      uint32_t rcv0 = __shfl_xor(snd0, 32);
      uint32_t rcv1 = __shfl_xor(snd1, 32);
      u32x4 pw;
      pw[0] = h ? rcv0 : own0;
      pw[1] = h ? rcv1 : own1;
      pw[2] = h ? own0 : rcv0;
      pw[3] = h ? own1 : rcv1;
      s8v pa = __builtin_bit_cast(s8v, pw);
      __builtin_amdgcn_s_setprio(1);
#pragma unroll
      for (int cf = 0; cf < 8; ++cf) {
        int c = cf * 32 + q5;
        s8v vfr = *(const s8v*)&Vb[cur][c * 64 + (((js * 2 + h) ^ (c & 7)) << 3)];
        oaccT[cf] = __builtin_amdgcn_mfma_f32_32x32x16_bf16(vfr, pa, oaccT[cf], 0, 0, 0);
      }
      __builtin_amdgcn_s_setprio(0);
    }
    __syncthreads();
  }
  // ---- epilogue: O^T/l -> LDS transpose -> att[n][p][c]
  float inv = 1.f / l_;
  u16* tl = &Kb[0][0];  // 128 q rows x 256 c, 512B rows, chunk16 ^= (q&7)
  __syncthreads();
  const int myq = w * 32 + q5;
#pragma unroll
  for (int cf = 0; cf < 8; ++cf)
#pragma unroll
    for (int g = 0; g < 4; ++g) {
      uint32_t w0 = cvtpk(oaccT[cf][4 * g + 0] * inv, oaccT[cf][4 * g + 1] * inv);
      uint32_t w1 = cvtpk(oaccT[cf][4 * g + 2] * inv, oaccT[cf][4 * g + 3] * inv);
      int ch = (cf * 4 + g) ^ (myq & 7);
      uint2 val; val.x = w0; val.y = w1;
      *(uint2*)&tl[myq * 256 + ch * 8 + h * 4] = val;
    }
  __syncthreads();
  const int qo = tid >> 1, hr = tid & 1;
  u16* obase = attb + nbase + (long)(qt * 128 + qo) * 256;
#pragma unroll
  for (int u = 0; u < 16; ++u) {
    int c16 = hr * 16 + u;
    u32x4 v = *(const u32x4*)&tl[qo * 256 + ((c16 ^ (qo & 7)) << 3)];
    *(u32x4*)(obase + c16 * 8) = v;
  }
}

// ---------------- temporal axial attention (unchanged) -----------------------------
__global__ __launch_bounds__(256) void tattn_kernel(const u16* __restrict__ qt,
                                                    const u16* __restrict__ kt,
                                                    const u16* __restrict__ vt,
                                                    u16* __restrict__ ot) {
  const int bi = blockIdx.x >> 10, hw = blockIdx.x & 1023;
  const long base = (long)bi * 4194304 + (long)hw * 256;
  __shared__ float qs[16][260], ks[16][260], vs[16][260];
  __shared__ u16 os[16][256];
  const int tid = threadIdx.x;
#pragma unroll
  for (int it = 0; it < 4; ++it) {
    int idx = it * 256 + tid;
    int t = idx >> 6, cv = idx & 63;
    long g = base + (long)t * 262144 + cv * 4;
    us4 a = *(const us4*)(qt + g);
    us4 b = *(const us4*)(kt + g);
    us4 c = *(const us4*)(vt + g);
#pragma unroll
    for (int j = 0; j < 4; ++j) {
      qs[t][cv * 4 + j] = bf2f(a[j]);
      ks[t][cv * 4 + j] = bf2f(b[j]);
      vs[t][cv * 4 + j] = bf2f(c[j]);
    }
  }
  __syncthreads();
  if (tid < 128) {
    const int h = tid >> 4, t = tid & 15;
    const int c0 = h * 32;
    float sc[16];
    float mx = -3.4e38f;
#pragma unroll
    for (int t2 = 0; t2 < 16; ++t2) {
      float d = 0.f;
#pragma unroll
      for (int dd = 0; dd < 32; ++dd) d += qs[t][c0 + dd] * ks[t2][c0 + dd];
      sc[t2] = d * 0.17677669529663687f;
      mx = fmaxf(mx, sc[t2]);
    }
    float sum = 0.f;
#pragma unroll
    for (int t2 = 0; t2 < 16; ++t2) { sc[t2] = __expf(sc[t2] - mx); sum += sc[t2]; }
    float inv = 1.f / sum;
#pragma unroll
    for (int dd = 0; dd < 32; ++dd) {
      float o = 0.f;
#pragma unroll
      for (int t2 = 0; t2 < 16; ++t2) o += sc[t2] * vs[t2][c0 + dd];
      os[t][c0 + dd] = f2bf(o * inv);
    }
  }
  __syncthreads();
#pragma unroll
  for (int it = 0; it < 4; ++it) {
    int idx = it * 256 + tid;
    int t = idx >> 6, cv = idx & 63;
    us4 o4;
#pragma unroll
    for (int j = 0; j < 4; ++j) o4[j] = os[t][cv * 4 + j];
    *(us4*)(ot + base + (long)t * 262144 + cv * 4) = o4;
  }
}

// ---------------- temporal final projection -> tmpT[b][co][s] bf16 -----------------
__global__ __launch_bounds__(512) void tfinal_kernel(
    const u16* __restrict__ ott, const u16* __restrict__ wbf,
    u16* __restrict__ tmpT) {
  __shared__ u16 ALDS[128 * 256];
  __shared__ u16 WLDS[2][64 * 256];
  const int bid = blockIdx.x;
  const int b = bid >> 7, st = bid & 127;
  const int s0 = st * 128;
  const int tid = threadIdx.x, w = tid >> 6, lane = tid & 63;
  const int lhi = lane >> 4, llo = lane & 15;
  const long bbase = (long)b * 4194304;

  const u16* otS = ott + bbase + (long)s0 * 256;
#pragma unroll
  for (int ii = 0; ii < 8; ++ii) {
    int i0 = (w * 8 + ii) * 64;
    int g = i0 + lane;
    int row = g >> 5, ch = g & 31;
    gl2lds16(otS + row * 256 + ((ch ^ (row & 7)) << 3), &ALDS[i0 * 8]);
  }
  __syncthreads();
  const int arow = w * 16 + llo;
  s8v qa[8];
#pragma unroll
  for (int kk = 0; kk < 8; ++kk)
    qa[kk] = *(const s8v*)&ALDS[arow * 256 + (((kk * 4 + lhi) ^ (arow & 7)) << 3)];

  auto stageW = [&](int t, int bu) {
    const u16* wsrc = wbf + 7 * 65536 + (long)t * 16384;
#pragma unroll
    for (int ii = 0; ii < 4; ++ii) {
      int i0 = (w * 4 + ii) * 64;
      int g = i0 + lane;
      int row = g >> 5, ch = g & 31;
      gl2lds16(wsrc + row * 256 + ((ch ^ (row & 7)) << 3), &WLDS[bu][i0 * 8]);
    }
  };
  stageW(0, 0);
  __syncthreads();
  u16* vtl = ALDS;  // safe: frags already in regs
  for (int t = 0; t < 4; ++t) {
    const int cur = t & 1;
    if (t < 3) stageW(t + 1, cur ^ 1);
    f32x4 acc[4] = {};
#pragma unroll
    for (int kk = 0; kk < 8; ++kk)
#pragma unroll
      for (int nf = 0; nf < 4; ++nf) {
        int row = nf * 16 + llo;
        s8v bb = *(const s8v*)&WLDS[cur][row * 256 + (((kk * 4 + lhi) ^ (row & 7)) << 3)];
        acc[nf] = __builtin_amdgcn_mfma_f32_16x16x32_bf16(qa[kk], bb, acc[nf], 0, 0, 0);
      }
#pragma unroll
    for (int nf = 0; nf < 4; ++nf) {
      int o = nf * 16 + llo;
#pragma unroll
      for (int r = 0; r < 4; ++r)
        vtl[o * 136 + w * 16 + lhi * 4 + r] = f2bf(acc[nf][r]);
    }
    __syncthreads();
    const int o0 = t * 64;
#pragma unroll
    for (int ii = 0; ii < 4; ++ii) {
      int i = ii * 512 + tid;
      int o = i >> 5, p4 = (i & 31) * 4;
      us4 uu;
#pragma unroll
      for (int j = 0; j < 4; ++j) uu[j] = vtl[o * 136 + p4 + j];
      *(us4*)(tmpT + bbase + (long)(o0 + o) * 16384 + s0 + p4) = uu;
    }
    __syncthreads();
  }
}

// ---------------- fused output: out = x + bo + bf + wo.att + tmpT ------------------
__global__ __launch_bounds__(256) void outproj_kernel(
    const float* __restrict__ x, const u16* __restrict__ attb,
    const u16* __restrict__ tmpT, const u16* __restrict__ wbf,
    const float* __restrict__ bo, const float* __restrict__ bf,
    float* __restrict__ out) {
  __shared__ u16 attL[64 * 256];
  const int u = blockIdx.x;
  const int wkx = (u & 7) * 256 + (u >> 3);  // XCD-chunk swizzle (2048 % 8 == 0)
  const int otile = wkx & 3, pt = (wkx >> 2) & 15, n = wkx >> 6;
  const int b = n >> 4;
  const int o0 = otile * 64, p0 = pt * 64;
  const int tid = threadIdx.x, w = tid >> 6, lane = tid & 63;
  const int lhi = lane >> 4, llo = lane & 15;
  const long nbase = (long)n * 262144;

  const u16* attS = attb + nbase + (long)p0 * 256;
#pragma unroll
  for (int ii = 0; ii < 8; ++ii) {
    int i0 = (w * 8 + ii) * 64;
    int g = i0 + lane;
    int row = g >> 5, ch = g & 31;
    gl2lds16(attS + row * 256 + ((ch ^ (row & 7)) << 3), &attL[i0 * 8]);
  }
  const u16* woR = wbf + 3 * 65536 + (long)(o0 + w * 16 + llo) * 256;
  s8v woa[8];
#pragma unroll
  for (int kk = 0; kk < 8; ++kk)
    woa[kk] = *(const s8v*)(woR + kk * 32 + lhi * 8);
  __syncthreads();
  f32x4 acc[4] = {};
#pragma unroll
  for (int kk = 0; kk < 8; ++kk)
#pragma unroll
    for (int nf = 0; nf < 4; ++nf) {
      int row = nf * 16 + llo;
      s8v b1 = *(const s8v*)&attL[row * 256 + (((kk * 4 + lhi) ^ (row & 7)) << 3)];
      acc[nf] = __builtin_amdgcn_mfma_f32_16x16x32_bf16(woa[kk], b1, acc[nf], 0, 0, 0);
    }
#pragma unroll
  for (int r = 0; r < 4; ++r) {
    int cp = o0 + w * 16 + lhi * 4 + r;          // output channel c'
    int co = ((n & 15) << 4) + (cp >> 4);        // temporal channel
    int tt = cp & 15;                            // temporal t
    float bias = bo[cp] + bf[co];
    const u16* tr = tmpT + (long)b * 4194304 + (long)co * 16384 + tt * 1024 + p0;
    const float* xr = x + nbase + (long)cp * 1024 + p0;
    float* orow = out + nbase + (long)cp * 1024 + p0;
#pragma unroll
    for (int nf = 0; nf < 4; ++nf) {
      int p = nf * 16 + llo;
      orow[p] = acc[nf][r] + bias + xr[p] + bf2f(tr[p]);
    }
  }
}

// =================================================================================
extern "C" void kernel_launch(void* const* d_in, const int* in_sizes, int n_in,
                              void* d_out, int out_size, void* d_ws, size_t ws_size,
                              hipStream_t stream) {
  const float* x     = (const float*)d_in[0];
  const float* gam   = (const float*)d_in[1];
  const float* bet   = (const float*)d_in[2];
  const float* wq_s  = (const float*)d_in[3];
  const float* bq_s  = (const float*)d_in[4];
  const float* wk_s  = (const float*)d_in[5];
  const float* bk_s  = (const float*)d_in[6];
  const float* wv_s  = (const float*)d_in[7];
  const float* bv_s  = (const float*)d_in[8];
  const float* wo_s  = (const float*)d_in[9];
  const float* bo_s  = (const float*)d_in[10];
  const float* wq_t  = (const float*)d_in[11];
  const float* wk_t  = (const float*)d_in[12];
  const float* wv_t  = (const float*)d_in[13];
  const float* wf_t  = (const float*)d_in[14];
  const float* bf_t  = (const float*)d_in[15];
  float* out = (float*)d_out;

  u16* qb   = (u16*)d_ws;           // [32][1024][256]
  u16* kb   = qb + 8388608;         // [32][1024][256]
  u16* vb   = kb + 8388608;         // [32][256][1024]
  u16* attb = vb + 8388608;         // [32][1024][256]
  u16* ottb = attb + 8388608;       // [2][16384][256]
  u16* wbf  = ottb + 8388608;       // 8 x [256][256] bf16
  u16* qtb  = wbf + 524288;         // [2][16384][256]
  u16* ktb  = qtb + 8388608;
  u16* vtb  = ktb + 8388608;
  float2* stats = (float2*)(vtb + 8388608);
  u16* tmpT = qtb;                  // dead post-tattn

  gn_stats_kernel<<<1024, 256, 0, stream>>>(x, stats);
  wprep_kernel<<<dim3(8, 4), 256, 0, stream>>>(wq_s, wk_s, wv_s, wo_s,
                                               wq_t, wk_t, wv_t, wf_t, wbf);
  qkvst_kernel<<<256, 512, 0, stream>>>(x, stats, gam, bet, wbf,
                                        bq_s, bk_s, bv_s, qb, kb, vb, qtb, ktb, vtb);
  flash_kernel<<<256, 256, 0, stream>>>(qb, kb, vb, attb);
  tattn_kernel<<<2048, 256, 0, stream>>>(qtb, ktb, vtb, ottb);
  tfinal_kernel<<<256, 512, 0, stream>>>(ottb, wbf, tmpT);
  outproj_kernel<<<2048, 256, 0, stream>>>(x, attb, tmpT, wbf, bo_s, bf_t, out);
}

// Round 12
// 193.187 us; speedup vs baseline: 1.2396x; 1.0675x over previous
//
#include <hip/hip_runtime.h>
#include <stdint.h>

typedef uint16_t u16;
typedef __attribute__((ext_vector_type(8))) short s8v;      // 8 x bf16 MFMA frag
typedef __attribute__((ext_vector_type(4))) float f32x4;
typedef __attribute__((ext_vector_type(16))) float f32x16;
typedef __attribute__((ext_vector_type(4))) unsigned short us4;
typedef __attribute__((ext_vector_type(4))) unsigned int u32x4;

__device__ __forceinline__ float bf2f(u16 u) {
  union { uint32_t i; float f; } x; x.i = ((uint32_t)u) << 16; return x.f;
}
__device__ __forceinline__ u16 f2bf(float f) {
  union { float f; uint32_t i; } x; x.f = f;
  uint32_t r = (x.i + 0x7FFFu + ((x.i >> 16) & 1u)) >> 16;
  return (u16)r;
}
__device__ __forceinline__ uint32_t cvtpk(float a, float b) {
  uint32_t r;
  asm("v_cvt_pk_bf16_f32 %0, %1, %2" : "=v"(r) : "v"(a), "v"(b));
  return r;
}
__device__ __forceinline__ void gl2lds16(const u16* g, u16* l) {
  __builtin_amdgcn_global_load_lds(
      (const __attribute__((address_space(1))) uint32_t*)g,
      (__attribute__((address_space(3))) uint32_t*)l, 16, 0, 0);
}

// ---------------- GroupNorm stats: one block per (n,g), 8192 contiguous floats ----
__global__ __launch_bounds__(256) void gn_stats_kernel(const float* __restrict__ x,
                                                       float2* __restrict__ stats) {
  const int tid = threadIdx.x;
  const float* p = x + (long)blockIdx.x * 8192;
  float s = 0.f, s2 = 0.f;
#pragma unroll
  for (int it = 0; it < 8; ++it) {
    float4 v = *(const float4*)(p + it * 1024 + tid * 4);
    s  += v.x + v.y + v.z + v.w;
    s2 += v.x * v.x + v.y * v.y + v.z * v.z + v.w * v.w;
  }
#pragma unroll
  for (int off = 32; off >= 1; off >>= 1) {
    s  += __shfl_down(s, off);
    s2 += __shfl_down(s2, off);
  }
  __shared__ float ps[4], ps2[4];
  const int wv = tid >> 6, lane = tid & 63;
  if (lane == 0) { ps[wv] = s; ps2[wv] = s2; }
  __syncthreads();
  if (tid == 0) {
    float S1 = ps[0] + ps[1] + ps[2] + ps[3];
    float S2 = ps2[0] + ps2[1] + ps2[2] + ps2[3];
    float mean = S1 * (1.f / 8192.f);
    float var = S2 * (1.f / 8192.f) - mean * mean;
    stats[blockIdx.x] = make_float2(mean, rsqrtf(var + 1e-6f));
  }
}

// ---------------- weight prep: bf16 copies [o][c]; mats 4..7 transposed -----------
__global__ __launch_bounds__(256) void wprep_kernel(
    const float* __restrict__ s0, const float* __restrict__ s1,
    const float* __restrict__ s2, const float* __restrict__ s3,
    const float* __restrict__ s4, const float* __restrict__ s5,
    const float* __restrict__ s6, const float* __restrict__ s7,
    u16* __restrict__ wbf) {
  const int mat = blockIdx.x, rb = blockIdx.y;
  const float* src = mat==0?s0:mat==1?s1:mat==2?s2:mat==3?s3:mat==4?s4:mat==5?s5:mat==6?s6:s7;
  u16* dst = wbf + mat * 65536 + rb * 16384;
  const int tid = threadIdx.x;
  if (mat < 4) {
    const float* sb = src + rb * 16384;
#pragma unroll
    for (int it = 0; it < 16; ++it) {
      int idx = it * 256 + tid;
      float4 v = *(const float4*)(sb + idx * 4);
      us4 o; o[0]=f2bf(v.x); o[1]=f2bf(v.y); o[2]=f2bf(v.z); o[3]=f2bf(v.w);
      *(us4*)(dst + idx * 4) = o;
    }
  } else {
    __shared__ u16 tl[64][264];
#pragma unroll
    for (int it = 0; it < 16; ++it) {
      int idx = it * 256 + tid;
      int c = idx >> 4, o4 = idx & 15;
      float4 v = *(const float4*)(src + c * 256 + rb * 64 + o4 * 4);
      tl[o4*4+0][c] = f2bf(v.x);
      tl[o4*4+1][c] = f2bf(v.y);
      tl[o4*4+2][c] = f2bf(v.z);
      tl[o4*4+3][c] = f2bf(v.w);
    }
    __syncthreads();
#pragma unroll
    for (int it = 0; it < 16; ++it) {
      int idx = it * 256 + tid;
      int o = idx >> 6, c4 = idx & 63;
      us4 u;
#pragma unroll
      for (int j = 0; j < 4; ++j) u[j] = tl[o][c4*4+j];
      *(us4*)(dst + o * 256 + c4 * 4) = u;
    }
  }
}

// ---------------- fused spatial+temporal q/k/v: one x read, 24 weight tiles -------
__global__ __launch_bounds__(512) void qkvst_kernel(
    const float* __restrict__ x, const float2* __restrict__ stats,
    const float* __restrict__ gamma, const float* __restrict__ beta,
    const u16* __restrict__ wbf,
    const float* __restrict__ bq, const float* __restrict__ bk, const float* __restrict__ bv,
    u16* __restrict__ qb, u16* __restrict__ kb, u16* __restrict__ vb,
    u16* __restrict__ qt, u16* __restrict__ kt, u16* __restrict__ vt) {
  __shared__ float gas[256], bes[256];
  __shared__ u16 ALDS[128 * 256];
  __shared__ u16 WLDS[2][64 * 256];
  const int bid = blockIdx.x;
  const int b = bid >> 7, st = bid & 127;
  const int s0 = st * 128;
  const int tt = s0 >> 10;              // temporal frame
  const int n = b * 16 + tt;            // spatial image
  const int p0 = s0 & 1023;             // hw offset
  const long bbase = (long)b * 4194304;
  const long nbase = (long)n * 262144;
  const int tid = threadIdx.x, w = tid >> 6, lane = tid & 63;
  const int lhi = lane >> 4, llo = lane & 15;

  if (tid < 256) {
    float2 stv = stats[n * 32 + (tid >> 3)];
    float ga = gamma[tid] * stv.y;
    gas[tid] = ga;
    bes[tid] = beta[tid] - stv.x * ga;
  }
  // ---- stage raw A (x^T bf16, swizzled)
  const float* xb = x + bbase + s0;
#pragma unroll
  for (int it = 0; it < 16; ++it) {
    int idx = it * 512 + tid;
    int p = idx & 127, c4 = idx >> 7;
    us4 o;
#pragma unroll
    for (int j = 0; j < 4; ++j)
      o[j] = f2bf(xb[(long)(c4 * 4 + j) * 16384 + p]);
    int ch = c4 >> 1;
    *(us4*)&ALDS[p * 256 + ((ch ^ (p & 7)) << 3) + ((c4 & 1) << 2)] = o;
  }
  __syncthreads();
  // ---- raw frags + in-register GN frags
  const int arow = w * 16 + llo;
  s8v ar[8], ag[8];
#pragma unroll
  for (int kk = 0; kk < 8; ++kk)
    ar[kk] = *(const s8v*)&ALDS[arow * 256 + (((kk * 4 + lhi) ^ (arow & 7)) << 3)];
#pragma unroll
  for (int kk = 0; kk < 8; ++kk) {
    const int cb = kk * 32 + lhi * 8;
    s8v gg;
#pragma unroll
    for (int j = 0; j < 8; ++j)
      gg[j] = (short)f2bf(bf2f((u16)ar[kk][j]) * gas[cb + j] + bes[cb + j]);
    ag[kk] = gg;
  }

  auto stageW4 = [&](int t, int bu) {
    const int mat = (t < 12) ? (t >> 2) : (4 + ((t - 12) >> 2));
    const int sub = (t < 12) ? (t & 3) : ((t - 12) & 3);
    const u16* wsrc = wbf + mat * 65536 + (long)sub * 16384;
#pragma unroll
    for (int ii = 0; ii < 4; ++ii) {
      int s = ii * 512 + tid;           // 0..2047 slots of 16B
      int row = s >> 5, ch = s & 31;
      gl2lds16(wsrc + row * 256 + ((ch ^ (row & 7)) << 3), &WLDS[bu][s * 8]);
    }
  };

  stageW4(0, 0);
  __syncthreads();

  u16* vtl = ALDS;  // reuse for v transpose [64 o][136]
  for (int t = 0; t < 24; ++t) {
    const int cur = t & 1;
    if (t < 23) stageW4(t + 1, cur ^ 1);
    f32x4 acc[4] = {};
    if (t < 12) {
#pragma unroll
      for (int kk = 0; kk < 8; ++kk)
#pragma unroll
        for (int nf = 0; nf < 4; ++nf) {
          int row = nf * 16 + llo;
          s8v bfr = *(const s8v*)&WLDS[cur][row * 256 + (((kk * 4 + lhi) ^ (row & 7)) << 3)];
          acc[nf] = __builtin_amdgcn_mfma_f32_16x16x32_bf16(ag[kk], bfr, acc[nf], 0, 0, 0);
        }
    } else {
#pragma unroll
      for (int kk = 0; kk < 8; ++kk)
#pragma unroll
        for (int nf = 0; nf < 4; ++nf) {
          int row = nf * 16 + llo;
          s8v bfr = *(const s8v*)&WLDS[cur][row * 256 + (((kk * 4 + lhi) ^ (row & 7)) << 3)];
          acc[nf] = __builtin_amdgcn_mfma_f32_16x16x32_bf16(ar[kk], bfr, acc[nf], 0, 0, 0);
        }
    }
    const int o0 = ((t < 12) ? (t & 3) : ((t - 12) & 3)) * 64;
    if (t < 8) {
      u16* dstb = (t < 4) ? qb : kb;
      const float* bias = (t < 4) ? bq : bk;
#pragma unroll
      for (int nf = 0; nf < 4; ++nf) {
        int o = o0 + nf * 16 + llo;
        float b_ = bias[o];
#pragma unroll
        for (int r = 0; r < 4; ++r)
          dstb[nbase + (long)(p0 + w * 16 + lhi * 4 + r) * 256 + o] = f2bf(acc[nf][r] + b_);
      }
    } else if (t < 12) {
#pragma unroll
      for (int nf = 0; nf < 4; ++nf) {
        int o = nf * 16 + llo;
        float b_ = bv[o0 + o];
#pragma unroll
        for (int r = 0; r < 4; ++r)
          vtl[o * 136 + w * 16 + lhi * 4 + r] = f2bf(acc[nf][r] + b_);
      }
      __syncthreads();
#pragma unroll
      for (int ii = 0; ii < 4; ++ii) {
        int i = ii * 512 + tid;
        int o = i >> 5, p4 = (i & 31) * 4;
        us4 u;
#pragma unroll
        for (int j = 0; j < 4; ++j) u[j] = vtl[o * 136 + p4 + j];
        *(us4*)(vb + nbase + (long)(o0 + o) * 1024 + p0 + p4) = u;
      }
    } else {
      u16* dstb = (t < 16) ? qt : (t < 20) ? kt : vt;
#pragma unroll
      for (int nf = 0; nf < 4; ++nf) {
        int o = o0 + nf * 16 + llo;
#pragma unroll
        for (int r = 0; r < 4; ++r)
          dstb[bbase + (long)(s0 + w * 16 + lhi * 4 + r) * 256 + o] = f2bf(acc[nf][r]);
      }
    }
    __syncthreads();
  }
}

// ---------------- flash spatial attention v12 = exact v4 (best measured, 64.6us) ---
// 256 blocks (32 n x 8 qtiles of 128 rows), 4 waves x 32 q-rows, 32x32x16 MFMA.
// Swapped QK^T (S^T), register softmax, in-register P redistribution, O^T accum.
__global__ __launch_bounds__(256, 1) void flash_kernel(const u16* __restrict__ qb,
                                                       const u16* __restrict__ kb,
                                                       const u16* __restrict__ vb,
                                                       u16* __restrict__ attb) {
  const int wg = blockIdx.x;
  const int swz = (wg & 7) * 32 + (wg >> 3);  // 4 n per XCD
  const int n = swz >> 3, qt = swz & 7;
  const int tid = threadIdx.x, w = tid >> 6, lane = tid & 63;
  const int q5 = lane & 31, h = lane >> 5;
  const long nbase = (long)n * 262144;

  __shared__ u16 Kb[2][64 * 256];  // [krow][c] 512B rows, chunk16 ^= (row&7)
  __shared__ u16 Vb[2][256 * 64];  // [c][j] 128B rows, chunk16 ^= (c&7)

  // Q fragments: B-operand, 32 q-rows per wave, k = kk*16 + h*8 + j
  const int qrow = qt * 128 + w * 32 + q5;
  const u16* qr = qb + nbase + (long)qrow * 256 + h * 8;
  s8v qa[16];
#pragma unroll
  for (int kk = 0; kk < 16; ++kk) qa[kk] = *(const s8v*)(qr + kk * 16);

  f32x16 oaccT[8] = {};   // O^T: c rows, q col (lane-uniform q)
  float m_ = -3.4e38f, l_ = 0.f;
  constexpr float CEXP = 0.09016844f;  // 0.0625 * log2(e)

  auto stageKV = [&](int jt2, int b) {
    const u16* kbase = kb + nbase + (long)jt2 * 16384;
    const u16* vbase = vb + nbase + (long)jt2 * 64;
#pragma unroll
    for (int ii = 0; ii < 8; ++ii) {
      int slot = ii * 256 + tid;
      int row = slot >> 5, ch = slot & 31;
      gl2lds16(kbase + (long)row * 256 + ((ch ^ (row & 7)) << 3), &Kb[b][slot * 8]);
    }
#pragma unroll
    for (int ii = 0; ii < 8; ++ii) {
      int slot = ii * 256 + tid;
      int c = slot >> 3, ch = slot & 7;
      gl2lds16(vbase + (long)c * 1024 + ((ch ^ (c & 7)) << 3), &Vb[b][slot * 8]);
    }
  };

  stageKV(0, 0);
  __syncthreads();

  for (int jt = 0; jt < 16; ++jt) {
    const int cur = jt & 1;
    if (jt < 15) stageKV(jt + 1, cur ^ 1);

    // ---- QK^T swapped: sacc[f] = S^T[k=f*32+...][q]
    f32x16 sacc[2] = {};
#pragma unroll
    for (int kk = 0; kk < 16; ++kk) {
#pragma unroll
      for (int f = 0; f < 2; ++f) {
        int krow = f * 32 + q5;
        s8v kfr = *(const s8v*)&Kb[cur][krow * 256 + (((kk * 2 + h) ^ (q5 & 7)) << 3)];
        sacc[f] = __builtin_amdgcn_mfma_f32_32x32x16_bf16(kfr, qa[kk], sacc[f], 0, 0, 0);
      }
    }
    // ---- softmax (raw-domain max, scale folded into exp2)
    float pm = sacc[0][0];
#pragma unroll
    for (int f = 0; f < 2; ++f)
#pragma unroll
      for (int r = 0; r < 16; ++r) pm = fmaxf(pm, sacc[f][r]);
    pm = fmaxf(pm, __shfl_xor(pm, 32));
    if (!__all(pm <= m_ + 128.f)) {   // defer-max: 128 raw = 8 scaled
      float scf = exp2f((m_ - pm) * CEXP);
      l_ *= scf;
#pragma unroll
      for (int cf = 0; cf < 8; ++cf)
#pragma unroll
        for (int r = 0; r < 16; ++r) oaccT[cf][r] *= scf;
      m_ = pm;
    }
    float rs = 0.f;
#pragma unroll
    for (int f = 0; f < 2; ++f)
#pragma unroll
      for (int r = 0; r < 16; ++r) {
        float p = exp2f((sacc[f][r] - m_) * CEXP);
        sacc[f][r] = p;
        rs += p;
      }
    rs += __shfl_xor(rs, 32);
    l_ += rs;
    // ---- pack P to bf16 pairs: pk[f][g][w] = (s=2w, s=2w+1) of reg group g
    uint32_t pk[2][4][2];
#pragma unroll
    for (int f = 0; f < 2; ++f)
#pragma unroll
      for (int g = 0; g < 4; ++g) {
        pk[f][g][0] = cvtpk(sacc[f][4 * g + 0], sacc[f][4 * g + 1]);
        pk[f][g][1] = cvtpk(sacc[f][4 * g + 2], sacc[f][4 * g + 3]);
      }
    // ---- PV: O^T += mfma(V^T, P) over 4 j-slices
#pragma unroll
    for (int js = 0; js < 4; ++js) {
      const int f = js >> 1, g0 = 2 * (js & 1);
      uint32_t own0 = h ? pk[f][g0 + 1][0] : pk[f][g0][0];
      uint32_t own1 = h ? pk[f][g0 + 1][1] : pk[f][g0][1];
      uint32_t snd0 = h ? pk[f][g0][0] : pk[f][g0 + 1][0];
      uint32_t snd1 = h ? pk[f][g0][1] : pk[f][g0 + 1][1];
      uint32_t rcv0 = __shfl_xor(snd0, 32);
      uint32_t rcv1 = __shfl_xor(snd1, 32);
      u32x4 pw;
      pw[0] = h ? rcv0 : own0;
      pw[1] = h ? rcv1 : own1;
      pw[2] = h ? own0 : rcv0;
      pw[3] = h ? own1 : rcv1;
      s8v pa = __builtin_bit_cast(s8v, pw);
#pragma unroll
      for (int cf = 0; cf < 8; ++cf) {
        int c = cf * 32 + q5;
        s8v vfr = *(const s8v*)&Vb[cur][c * 64 + (((js * 2 + h) ^ (c & 7)) << 3)];
        oaccT[cf] = __builtin_amdgcn_mfma_f32_32x32x16_bf16(vfr, pa, oaccT[cf], 0, 0, 0);
      }
    }
    __syncthreads();
  }
  // ---- epilogue: O^T/l -> LDS transpose -> att[n][p][c]
  float inv = 1.f / l_;
  u16* tl = &Kb[0][0];  // 128 q rows x 256 c, 512B rows, chunk16 ^= (q&7)
  __syncthreads();
  const int myq = w * 32 + q5;
#pragma unroll
  for (int cf = 0; cf < 8; ++cf)
#pragma unroll
    for (int g = 0; g < 4; ++g) {
      uint32_t w0 = cvtpk(oaccT[cf][4 * g + 0] * inv, oaccT[cf][4 * g + 1] * inv);
      uint32_t w1 = cvtpk(oaccT[cf][4 * g + 2] * inv, oaccT[cf][4 * g + 3] * inv);
      int ch = (cf * 4 + g) ^ (myq & 7);
      uint2 val; val.x = w0; val.y = w1;
      *(uint2*)&tl[myq * 256 + ch * 8 + h * 4] = val;
    }
  __syncthreads();
  const int qo = tid >> 1, hr = tid & 1;
  u16* obase = attb + nbase + (long)(qt * 128 + qo) * 256;
#pragma unroll
  for (int u = 0; u < 16; ++u) {
    int c16 = hr * 16 + u;
    u32x4 v = *(const u32x4*)&tl[qo * 256 + ((c16 ^ (qo & 7)) << 3)];
    *(u32x4*)(obase + c16 * 8) = v;
  }
}

// ---------------- temporal axial attention (unchanged) -----------------------------
__global__ __launch_bounds__(256) void tattn_kernel(const u16* __restrict__ qt,
                                                    const u16* __restrict__ kt,
                                                    const u16* __restrict__ vt,
                                                    u16* __restrict__ ot) {
  const int bi = blockIdx.x >> 10, hw = blockIdx.x & 1023;
  const long base = (long)bi * 4194304 + (long)hw * 256;
  __shared__ float qs[16][260], ks[16][260], vs[16][260];
  __shared__ u16 os[16][256];
  const int tid = threadIdx.x;
#pragma unroll
  for (int it = 0; it < 4; ++it) {
    int idx = it * 256 + tid;
    int t = idx >> 6, cv = idx & 63;
    long g = base + (long)t * 262144 + cv * 4;
    us4 a = *(const us4*)(qt + g);
    us4 b = *(const us4*)(kt + g);
    us4 c = *(const us4*)(vt + g);
#pragma unroll
    for (int j = 0; j < 4; ++j) {
      qs[t][cv * 4 + j] = bf2f(a[j]);
      ks[t][cv * 4 + j] = bf2f(b[j]);
      vs[t][cv * 4 + j] = bf2f(c[j]);
    }
  }
  __syncthreads();
  if (tid < 128) {
    const int h = tid >> 4, t = tid & 15;
    const int c0 = h * 32;
    float sc[16];
    float mx = -3.4e38f;
#pragma unroll
    for (int t2 = 0; t2 < 16; ++t2) {
      float d = 0.f;
#pragma unroll
      for (int dd = 0; dd < 32; ++dd) d += qs[t][c0 + dd] * ks[t2][c0 + dd];
      sc[t2] = d * 0.17677669529663687f;
      mx = fmaxf(mx, sc[t2]);
    }
    float sum = 0.f;
#pragma unroll
    for (int t2 = 0; t2 < 16; ++t2) { sc[t2] = __expf(sc[t2] - mx); sum += sc[t2]; }
    float inv = 1.f / sum;
#pragma unroll
    for (int dd = 0; dd < 32; ++dd) {
      float o = 0.f;
#pragma unroll
      for (int t2 = 0; t2 < 16; ++t2) o += sc[t2] * vs[t2][c0 + dd];
      os[t][c0 + dd] = f2bf(o * inv);
    }
  }
  __syncthreads();
#pragma unroll
  for (int it = 0; it < 4; ++it) {
    int idx = it * 256 + tid;
    int t = idx >> 6, cv = idx & 63;
    us4 o4;
#pragma unroll
    for (int j = 0; j < 4; ++j) o4[j] = os[t][cv * 4 + j];
    *(us4*)(ot + base + (long)t * 262144 + cv * 4) = o4;
  }
}

// ---------------- temporal final projection -> tmpT[b][co][s] bf16 -----------------
__global__ __launch_bounds__(512) void tfinal_kernel(
    const u16* __restrict__ ott, const u16* __restrict__ wbf,
    u16* __restrict__ tmpT) {
  __shared__ u16 ALDS[128 * 256];
  __shared__ u16 WLDS[2][64 * 256];
  const int bid = blockIdx.x;
  const int b = bid >> 7, st = bid & 127;
  const int s0 = st * 128;
  const int tid = threadIdx.x, w = tid >> 6, lane = tid & 63;
  const int lhi = lane >> 4, llo = lane & 15;
  const long bbase = (long)b * 4194304;

  const u16* otS = ott + bbase + (long)s0 * 256;
#pragma unroll
  for (int ii = 0; ii < 8; ++ii) {
    int i0 = (w * 8 + ii) * 64;
    int g = i0 + lane;
    int row = g >> 5, ch = g & 31;
    gl2lds16(otS + row * 256 + ((ch ^ (row & 7)) << 3), &ALDS[i0 * 8]);
  }
  __syncthreads();
  const int arow = w * 16 + llo;
  s8v qa[8];
#pragma unroll
  for (int kk = 0; kk < 8; ++kk)
    qa[kk] = *(const s8v*)&ALDS[arow * 256 + (((kk * 4 + lhi) ^ (arow & 7)) << 3)];

  auto stageW = [&](int t, int bu) {
    const u16* wsrc = wbf + 7 * 65536 + (long)t * 16384;
#pragma unroll
    for (int ii = 0; ii < 4; ++ii) {
      int i0 = (w * 4 + ii) * 64;
      int g = i0 + lane;
      int row = g >> 5, ch = g & 31;
      gl2lds16(wsrc + row * 256 + ((ch ^ (row & 7)) << 3), &WLDS[bu][i0 * 8]);
    }
  };
  stageW(0, 0);
  __syncthreads();
  u16* vtl = ALDS;  // safe: frags already in regs
  for (int t = 0; t < 4; ++t) {
    const int cur = t & 1;
    if (t < 3) stageW(t + 1, cur ^ 1);
    f32x4 acc[4] = {};
#pragma unroll
    for (int kk = 0; kk < 8; ++kk)
#pragma unroll
      for (int nf = 0; nf < 4; ++nf) {
        int row = nf * 16 + llo;
        s8v bb = *(const s8v*)&WLDS[cur][row * 256 + (((kk * 4 + lhi) ^ (row & 7)) << 3)];
        acc[nf] = __builtin_amdgcn_mfma_f32_16x16x32_bf16(qa[kk], bb, acc[nf], 0, 0, 0);
      }
#pragma unroll
    for (int nf = 0; nf < 4; ++nf) {
      int o = nf * 16 + llo;
#pragma unroll
      for (int r = 0; r < 4; ++r)
        vtl[o * 136 + w * 16 + lhi * 4 + r] = f2bf(acc[nf][r]);
    }
    __syncthreads();
    const int o0 = t * 64;
#pragma unroll
    for (int ii = 0; ii < 4; ++ii) {
      int i = ii * 512 + tid;
      int o = i >> 5, p4 = (i & 31) * 4;
      us4 uu;
#pragma unroll
      for (int j = 0; j < 4; ++j) uu[j] = vtl[o * 136 + p4 + j];
      *(us4*)(tmpT + bbase + (long)(o0 + o) * 16384 + s0 + p4) = uu;
    }
    __syncthreads();
  }
}

// ---------------- fused output: out = x + bo + bf + wo.att + tmpT ------------------
__global__ __launch_bounds__(256) void outproj_kernel(
    const float* __restrict__ x, const u16* __restrict__ attb,
    const u16* __restrict__ tmpT, const u16* __restrict__ wbf,
    const float* __restrict__ bo, const float* __restrict__ bf,
    float* __restrict__ out) {
  __shared__ u16 attL[64 * 256];
  const int u = blockIdx.x;
  const int wkx = (u & 7) * 256 + (u >> 3);  // XCD-chunk swizzle (2048 % 8 == 0)
  const int otile = wkx & 3, pt = (wkx >> 2) & 15, n = wkx >> 6;
  const int b = n >> 4;
  const int o0 = otile * 64, p0 = pt * 64;
  const int tid = threadIdx.x, w = tid >> 6, lane = tid & 63;
  const int lhi = lane >> 4, llo = lane & 15;
  const long nbase = (long)n * 262144;

  const u16* attS = attb + nbase + (long)p0 * 256;
#pragma unroll
  for (int ii = 0; ii < 8; ++ii) {
    int i0 = (w * 8 + ii) * 64;
    int g = i0 + lane;
    int row = g >> 5, ch = g & 31;
    gl2lds16(attS + row * 256 + ((ch ^ (row & 7)) << 3), &attL[i0 * 8]);
  }
  const u16* woR = wbf + 3 * 65536 + (long)(o0 + w * 16 + llo) * 256;
  s8v woa[8];
#pragma unroll
  for (int kk = 0; kk < 8; ++kk)
    woa[kk] = *(const s8v*)(woR + kk * 32 + lhi * 8);
  __syncthreads();
  f32x4 acc[4] = {};
#pragma unroll
  for (int kk = 0; kk < 8; ++kk)
#pragma unroll
    for (int nf = 0; nf < 4; ++nf) {
      int row = nf * 16 + llo;
      s8v b1 = *(const s8v*)&attL[row * 256 + (((kk * 4 + lhi) ^ (row & 7)) << 3)];
      acc[nf] = __builtin_amdgcn_mfma_f32_16x16x32_bf16(woa[kk], b1, acc[nf], 0, 0, 0);
    }
#pragma unroll
  for (int r = 0; r < 4; ++r) {
    int cp = o0 + w * 16 + lhi * 4 + r;          // output channel c'
    int co = ((n & 15) << 4) + (cp >> 4);        // temporal channel
    int tt = cp & 15;                            // temporal t
    float bias = bo[cp] + bf[co];
    const u16* tr = tmpT + (long)b * 4194304 + (long)co * 16384 + tt * 1024 + p0;
    const float* xr = x + nbase + (long)cp * 1024 + p0;
    float* orow = out + nbase + (long)cp * 1024 + p0;
#pragma unroll
    for (int nf = 0; nf < 4; ++nf) {
      int p = nf * 16 + llo;
      orow[p] = acc[nf][r] + bias + xr[p] + bf2f(tr[p]);
    }
  }
}

// =================================================================================
extern "C" void kernel_launch(void* const* d_in, const int* in_sizes, int n_in,
                              void* d_out, int out_size, void* d_ws, size_t ws_size,
                              hipStream_t stream) {
  const float* x     = (const float*)d_in[0];
  const float* gam   = (const float*)d_in[1];
  const float* bet   = (const float*)d_in[2];
  const float* wq_s  = (const float*)d_in[3];
  const float* bq_s  = (const float*)d_in[4];
  const float* wk_s  = (const float*)d_in[5];
  const float* bk_s  = (const float*)d_in[6];
  const float* wv_s  = (const float*)d_in[7];
  const float* bv_s  = (const float*)d_in[8];
  const float* wo_s  = (const float*)d_in[9];
  const float* bo_s  = (const float*)d_in[10];
  const float* wq_t  = (const float*)d_in[11];
  const float* wk_t  = (const float*)d_in[12];
  const float* wv_t  = (const float*)d_in[13];
  const float* wf_t  = (const float*)d_in[14];
  const float* bf_t  = (const float*)d_in[15];
  float* out = (float*)d_out;

  u16* qb   = (u16*)d_ws;           // [32][1024][256]
  u16* kb   = qb + 8388608;         // [32][1024][256]
  u16* vb   = kb + 8388608;         // [32][256][1024]
  u16* attb = vb + 8388608;         // [32][1024][256]
  u16* ottb = attb + 8388608;       // [2][16384][256]
  u16* wbf  = ottb + 8388608;       // 8 x [256][256] bf16
  u16* qtb  = wbf + 524288;         // [2][16384][256]
  u16* ktb  = qtb + 8388608;
  u16* vtb  = ktb + 8388608;
  float2* stats = (float2*)(vtb + 8388608);
  u16* tmpT = qtb;                  // dead post-tattn

  gn_stats_kernel<<<1024, 256, 0, stream>>>(x, stats);
  wprep_kernel<<<dim3(8, 4), 256, 0, stream>>>(wq_s, wk_s, wv_s, wo_s,
                                               wq_t, wk_t, wv_t, wf_t, wbf);
  qkvst_kernel<<<256, 512, 0, stream>>>(x, stats, gam, bet, wbf,
                                        bq_s, bk_s, bv_s, qb, kb, vb, qtb, ktb, vtb);
  flash_kernel<<<256, 256, 0, stream>>>(qb, kb, vb, attb);
  tattn_kernel<<<2048, 256, 0, stream>>>(qtb, ktb, vtb, ottb);
  tfinal_kernel<<<256, 512, 0, stream>>>(ottb, wbf, tmpT);
  outproj_kernel<<<2048, 256, 0, stream>>>(x, attb, tmpT, wbf, bo_s, bf_t, out);
}